// Round 1
// baseline (100.898 us; speedup 1.0000x reference)
//
#include <hip/hip_runtime.h>
#include <math.h>

// CuboidAlignment: B independent tiny problems.
// Analytic simplifications vs reference:
//  - perspective transform is exactly-determined => xf == cuboid axes exactly
//  - 2x2 Procrustes SVD closed form: s*R = [[A,-B],[B,A]]/var  (A=K00+K11, B=K01-K10)
//  - t = c1 - s*R*c1 (reference sets c2=c1), so out = centroid + s*R*(Cu*scale)
// Ordering-critical path (floor_xy, centroid, atan2 keys) in double to match the
// float64 numpy reference's argsort; everything else float.

#define FLOOR_Z_VAL (-1.6)

__global__ __launch_bounds__(256) void cuboid_kernel(
    const float* __restrict__ top_c,   // (B,4,2)
    const float* __restrict__ bot_c,   // (B,4,2)
    const float* __restrict__ cub,     // (1,4,2)
    float* __restrict__ out,           // top (B,4,3) then bottom (B,4,3)
    int B)
{
    const double PI_D = 3.14159265358979323846264338327950288;
    int b = blockIdx.x * blockDim.x + threadIdx.x;
    if (b >= B) return;

    float4 bc0 = *(const float4*)(bot_c + (size_t)b * 8);
    float4 bc1 = *(const float4*)(bot_c + (size_t)b * 8 + 4);
    float4 tc0 = *(const float4*)(top_c + (size_t)b * 8);
    float4 tc1 = *(const float4*)(top_c + (size_t)b * 8 + 4);

    double bu[4] = {(double)bc0.x, (double)bc0.z, (double)bc1.x, (double)bc1.z};
    double bv[4] = {(double)bc0.y, (double)bc0.w, (double)bc1.y, (double)bc1.w};
    float  tv[4] = {tc0.y, tc0.w, tc1.y, tc1.w};

    // floor_xy in double (ordering-critical)
    double X[4], Y[4];
#pragma unroll
    for (int i = 0; i < 4; ++i) {
        double u = bu[i] * PI_D;
        double v = bv[i] * (-0.5 * PI_D);
        double c = FLOOR_Z_VAL / tan(v);
        double su, cu;
        sincos(u, &su, &cu);
        X[i] = c * su;
        Y[i] = -c * cu;
    }
    double cx = 0.25 * (X[0] + X[1] + X[2] + X[3]);
    double cy = 0.25 * (Y[0] + Y[1] + Y[2] + Y[3]);

    // argsort keys (double atan2 to match f64 reference ordering)
    double key[4];
#pragma unroll
    for (int i = 0; i < 4; ++i)
        key[i] = atan2(X[i] - cx, (Y[i] - cy) + 1e-12);

    int rank[4];
#pragma unroll
    for (int k = 0; k < 4; ++k) {
        int r = 0;
#pragma unroll
        for (int m = 0; m < 4; ++m) {
            if (m == k) continue;
            r += ((key[m] < key[k]) || ((key[m] == key[k]) && (m < k))) ? 1 : 0;
        }
        rank[k] = r;
    }

    // float stage: scale, ceil_z, procrustes
    float Xf[4], Yf[4];
#pragma unroll
    for (int i = 0; i < 4; ++i) { Xf[i] = (float)X[i]; Yf[i] = (float)Y[i]; }
    float cxf = (float)cx, cyf = (float)cy;

    float d01x = Xf[0]-Xf[1], d01y = Yf[0]-Yf[1];
    float d12x = Xf[1]-Xf[2], d12y = Yf[1]-Yf[2];
    float d23x = Xf[2]-Xf[3], d23y = Yf[2]-Yf[3];
    float d30x = Xf[3]-Xf[0], d30y = Yf[3]-Yf[0];
    float ax1 = sqrtf(d01x*d01x + d01y*d01y);
    float ay1 = sqrtf(d12x*d12x + d12y*d12y);
    float ax2 = sqrtf(d23x*d23x + d23y*d23y);
    float ay2 = sqrtf(d30x*d30x + d30y*d30y);
    float s0 = 0.25f * (ay1 + ay2);   // scales x coords (a_y/2)
    float s1 = 0.25f * (ax1 + ax2);   // scales y coords (a_x/2)

    float ceil_z = 0.f;
#pragma unroll
    for (int i = 0; i < 4; ++i) {
        float cn = sqrtf(Xf[i]*Xf[i] + Yf[i]*Yf[i]);
        ceil_z += cn * tanf(tv[i] * (-0.5f * 3.14159265358979f));
    }
    ceil_z *= 0.25f;

    float Cux[4], Cuy[4];
#pragma unroll
    for (int k = 0; k < 4; ++k) { Cux[k] = cub[2*k]; Cuy[k] = cub[2*k+1]; }

    // rect0 per original index k (pairing with floor_xy[k] is permutation-invariant)
    float rx[4], ry[4];
#pragma unroll
    for (int k = 0; k < 4; ++k) {
        rx[k] = Cux[k] * s0 + cxf;
        ry[k] = Cuy[k] * s1 + cyf;
    }
    float c1x = 0.25f*(rx[0]+rx[1]+rx[2]+rx[3]);
    float c1y = 0.25f*(ry[0]+ry[1]+ry[2]+ry[3]);

    float var = 0.f, K00 = 0.f, K01 = 0.f, K10 = 0.f, K11 = 0.f;
#pragma unroll
    for (int k = 0; k < 4; ++k) {
        float p1x = rx[k]-c1x, p1y = ry[k]-c1y;
        float p2x = Xf[k]-c1x, p2y = Yf[k]-c1y;
        var += p1x*p1x + p1y*p1y;
        K00 += p1x*p2x; K01 += p1x*p2y;
        K10 += p1y*p2x; K11 += p1y*p2y;
    }
    float A  = K00 + K11;
    float Bb = K01 - K10;
    float ivar = 1.f / var;
    float m00 = A * ivar, m01 = -Bb * ivar;
    float m10 = Bb * ivar, m11 = A * ivar;

    float px[4], py[4];
#pragma unroll
    for (int k = 0; k < 4; ++k) {
        float dx = rx[k] - c1x, dy = ry[k] - c1y;
        px[k] = m00*dx + m01*dy + c1x;
        py[k] = m10*dx + m11*dy + c1y;
    }

    // place point k at slot rank[k] (predicated selects -> registers, no scratch)
    float ox[4], oy[4];
#pragma unroll
    for (int j = 0; j < 4; ++j) {
        float vx = 0.f, vy = 0.f;
#pragma unroll
        for (int k = 0; k < 4; ++k) {
            bool sel = (rank[k] == j);
            vx = sel ? px[k] : vx;
            vy = sel ? py[k] : vy;
        }
        ox[j] = vx; oy[j] = vy;
    }

    float fz = (float)FLOOR_Z_VAL;
    float4* ot4 = (float4*)(out + (size_t)b * 12);
    ot4[0] = make_float4(ox[0], oy[0], ceil_z, ox[1]);
    ot4[1] = make_float4(oy[1], ceil_z, ox[2], oy[2]);
    ot4[2] = make_float4(ceil_z, ox[3], oy[3], ceil_z);
    float4* ob4 = (float4*)(out + (size_t)B * 12 + (size_t)b * 12);
    ob4[0] = make_float4(ox[0], oy[0], fz, ox[1]);
    ob4[1] = make_float4(oy[1], fz, ox[2], oy[2]);
    ob4[2] = make_float4(fz, ox[3], oy[3], fz);
}

extern "C" void kernel_launch(void* const* d_in, const int* in_sizes, int n_in,
                              void* d_out, int out_size, void* d_ws, size_t ws_size,
                              hipStream_t stream) {
    const float* top_c = (const float*)d_in[0];
    const float* bot_c = (const float*)d_in[1];
    const float* cub   = (const float*)d_in[2];
    float* out = (float*)d_out;
    int B = in_sizes[0] / 8;
    int block = 256;
    int grid = (B + block - 1) / block;
    hipLaunchKernelGGL(cuboid_kernel, dim3(grid), dim3(block), 0, stream,
                       top_c, bot_c, cub, out, B);
}

// Round 2
// 97.698 us; speedup vs baseline: 1.0328x; 1.0328x over previous
//
#include <hip/hip_runtime.h>
#include <math.h>

// CuboidAlignment, R1: replace f64 libm (tan/sincos/atan2) with:
//  - custom sincospi(x) for x in (-1,1): n=rint(2x), r=x-n/2 in [-.25,.25],
//    Taylor polys for sin(pi r)/cos(pi r) (<=2ulp, matches numpy f64 ordering)
//  - tan(v) via sinpi/cospi ratio; c = -1.6*cospi/sinpi
//  - argsort ranks via exact sign/cross-product comparator (no atan2)
// Analytic shortcuts (verified passing R0): perspective transform is exact
// interpolation => xf == cuboid axes; 2x2 Procrustes closed form
// s*R = [[A,-B],[B,A]]/var, A=K00+K11, B=K01-K10, t = c1 - s*R*c1.

#define FLOOR_Z_VAL (-1.6)

__device__ __forceinline__ void sincospi_d(double x, double* sp, double* cp) {
    double n = rint(2.0 * x);
    double r = fma(n, -0.5, x);      // r in [-0.25, 0.25]
    int q = ((int)n) & 3;
    double t = r * r;
    // sin(pi r) = r * ps(t)
    double ps = -2.1915353447830215e-05;
    ps = fma(ps, t,  4.6630280576761010e-04);
    ps = fma(ps, t, -7.3704309457143504e-03);
    ps = fma(ps, t,  8.2145886611128228e-02);
    ps = fma(ps, t, -5.9926452932079207e-01);
    ps = fma(ps, t,  2.5501640398773455e+00);
    ps = fma(ps, t, -5.1677127800499700e+00);
    ps = fma(ps, t,  3.1415926535897931e+00);
    double s = r * ps;
    // cos(pi r) = pc(t)
    double pc =  4.3030695870329470e-06;
    pc = fma(pc, t, -1.0463810492484570e-04);
    pc = fma(pc, t,  1.9295743094039231e-03);
    pc = fma(pc, t, -2.5806891390014061e-02);
    pc = fma(pc, t,  2.3533063035889320e-01);
    pc = fma(pc, t, -1.3352627688545894e+00);
    pc = fma(pc, t,  4.0587121264167682e+00);
    pc = fma(pc, t, -4.9348022005446793e+00);
    double c = fma(pc, t, 1.0);
    // quadrant fixup: sin(pi x): q0:+s q1:+c q2:-s q3:-c ; cos: q0:+c q1:-s q2:-c q3:+s
    double bs = (q & 1) ? c : s;
    double bc = (q & 1) ? s : c;
    *sp = (q & 2) ? -bs : bs;
    *cp = ((q + 1) & 2) ? -bc : bc;
}

__global__ __launch_bounds__(256) void cuboid_kernel(
    const float* __restrict__ top_c,   // (B,4,2)
    const float* __restrict__ bot_c,   // (B,4,2)
    const float* __restrict__ cub,     // (1,4,2)
    float* __restrict__ out,           // top (B,4,3) then bottom (B,4,3)
    int B)
{
    int b = blockIdx.x * blockDim.x + threadIdx.x;
    if (b >= B) return;

    float4 bc0 = *(const float4*)(bot_c + (size_t)b * 8);
    float4 bc1 = *(const float4*)(bot_c + (size_t)b * 8 + 4);
    float4 tc0 = *(const float4*)(top_c + (size_t)b * 8);
    float4 tc1 = *(const float4*)(top_c + (size_t)b * 8 + 4);

    double bu[4] = {(double)bc0.x, (double)bc0.z, (double)bc1.x, (double)bc1.z};
    double bv[4] = {(double)bc0.y, (double)bc0.w, (double)bc1.y, (double)bc1.w};
    float  tv[4] = {tc0.y, tc0.w, tc1.y, tc1.w};

    // floor_xy in f64 (ordering-critical), via sincospi
    double X[4], Y[4];
#pragma unroll
    for (int i = 0; i < 4; ++i) {
        double su, cu, sv, cv;
        sincospi_d(bu[i], &su, &cu);
        sincospi_d(-0.5 * bv[i], &sv, &cv);
        double c = (FLOOR_Z_VAL * cv) / sv;   // floor_z / tan(v)
        X[i] = c * su;
        Y[i] = -c * cu;
    }
    double cx = 0.25 * (X[0] + X[1] + X[2] + X[3]);
    double cy = 0.25 * (Y[0] + Y[1] + Y[2] + Y[3]);

    // argsort of atan2(X-cx, Y-cy+1e-12) without atan2:
    // half h=0 iff angle<0 iff (X-cx)<0 ; within half, cross-product sign.
    double hx[4], hy[4];
    int h[4];
#pragma unroll
    for (int i = 0; i < 4; ++i) {
        hx[i] = (Y[i] - cy) + 1e-12;   // "x" arg of atan2
        hy[i] = X[i] - cx;             // "y" arg of atan2
        h[i] = (hy[i] < 0.0) ? 0 : 1;
    }
    int rank[4];
#pragma unroll
    for (int k = 0; k < 4; ++k) {
        int r = 0;
#pragma unroll
        for (int m = 0; m < 4; ++m) {
            if (m == k) continue;
            bool before;
            if (h[m] != h[k]) {
                before = h[m] < h[k];
            } else {
                double cr = hx[m] * hy[k] - hy[m] * hx[k];  // >0 => theta_m < theta_k
                before = (cr > 0.0) || (cr == 0.0 && m < k);
            }
            r += before ? 1 : 0;
        }
        rank[k] = r;
    }

    // float stage: scale, ceil_z, procrustes
    float Xf[4], Yf[4];
#pragma unroll
    for (int i = 0; i < 4; ++i) { Xf[i] = (float)X[i]; Yf[i] = (float)Y[i]; }
    float cxf = (float)cx, cyf = (float)cy;

    float d01x = Xf[0]-Xf[1], d01y = Yf[0]-Yf[1];
    float d12x = Xf[1]-Xf[2], d12y = Yf[1]-Yf[2];
    float d23x = Xf[2]-Xf[3], d23y = Yf[2]-Yf[3];
    float d30x = Xf[3]-Xf[0], d30y = Yf[3]-Yf[0];
    float ax1 = sqrtf(d01x*d01x + d01y*d01y);
    float ay1 = sqrtf(d12x*d12x + d12y*d12y);
    float ax2 = sqrtf(d23x*d23x + d23y*d23y);
    float ay2 = sqrtf(d30x*d30x + d30y*d30y);
    float s0 = 0.25f * (ay1 + ay2);   // scales x coords (a_y/2)
    float s1 = 0.25f * (ax1 + ax2);   // scales y coords (a_x/2)

    float ceil_z = 0.f;
#pragma unroll
    for (int i = 0; i < 4; ++i) {
        float cn = sqrtf(Xf[i]*Xf[i] + Yf[i]*Yf[i]);
        ceil_z += cn * tanf(tv[i] * (-0.5f * 3.14159265358979f));
    }
    ceil_z *= 0.25f;

    float Cux[4], Cuy[4];
#pragma unroll
    for (int k = 0; k < 4; ++k) { Cux[k] = cub[2*k]; Cuy[k] = cub[2*k+1]; }

    float rx[4], ry[4];
#pragma unroll
    for (int k = 0; k < 4; ++k) {
        rx[k] = Cux[k] * s0 + cxf;
        ry[k] = Cuy[k] * s1 + cyf;
    }
    float c1x = 0.25f*(rx[0]+rx[1]+rx[2]+rx[3]);
    float c1y = 0.25f*(ry[0]+ry[1]+ry[2]+ry[3]);

    float var = 0.f, K00 = 0.f, K01 = 0.f, K10 = 0.f, K11 = 0.f;
#pragma unroll
    for (int k = 0; k < 4; ++k) {
        float p1x = rx[k]-c1x, p1y = ry[k]-c1y;
        float p2x = Xf[k]-c1x, p2y = Yf[k]-c1y;
        var += p1x*p1x + p1y*p1y;
        K00 += p1x*p2x; K01 += p1x*p2y;
        K10 += p1y*p2x; K11 += p1y*p2y;
    }
    float A  = K00 + K11;
    float Bb = K01 - K10;
    float ivar = 1.f / var;
    float m00 = A * ivar, m01 = -Bb * ivar;
    float m10 = Bb * ivar, m11 = A * ivar;

    float px[4], py[4];
#pragma unroll
    for (int k = 0; k < 4; ++k) {
        float dx = rx[k] - c1x, dy = ry[k] - c1y;
        px[k] = m00*dx + m01*dy + c1x;
        py[k] = m10*dx + m11*dy + c1y;
    }

    // place point k at slot rank[k] (predicated selects -> registers)
    float ox[4], oy[4];
#pragma unroll
    for (int j = 0; j < 4; ++j) {
        float vx = 0.f, vy = 0.f;
#pragma unroll
        for (int k = 0; k < 4; ++k) {
            bool sel = (rank[k] == j);
            vx = sel ? px[k] : vx;
            vy = sel ? py[k] : vy;
        }
        ox[j] = vx; oy[j] = vy;
    }

    float fz = (float)FLOOR_Z_VAL;
    float4* ot4 = (float4*)(out + (size_t)b * 12);
    ot4[0] = make_float4(ox[0], oy[0], ceil_z, ox[1]);
    ot4[1] = make_float4(oy[1], ceil_z, ox[2], oy[2]);
    ot4[2] = make_float4(ceil_z, ox[3], oy[3], ceil_z);
    float4* ob4 = (float4*)(out + (size_t)B * 12 + (size_t)b * 12);
    ob4[0] = make_float4(ox[0], oy[0], fz, ox[1]);
    ob4[1] = make_float4(oy[1], fz, ox[2], oy[2]);
    ob4[2] = make_float4(fz, ox[3], oy[3], fz);
}

extern "C" void kernel_launch(void* const* d_in, const int* in_sizes, int n_in,
                              void* d_out, int out_size, void* d_ws, size_t ws_size,
                              hipStream_t stream) {
    const float* top_c = (const float*)d_in[0];
    const float* bot_c = (const float*)d_in[1];
    const float* cub   = (const float*)d_in[2];
    float* out = (float*)d_out;
    int B = in_sizes[0] / 8;
    int block = 256;
    int grid = (B + block - 1) / block;
    hipLaunchKernelGGL(cuboid_kernel, dim3(grid), dim3(block), 0, stream,
                       top_c, bot_c, cub, out, B);
}